// Round 4
// baseline (495.472 us; speedup 1.0000x reference)
//
#include <hip/hip_runtime.h>
#include <math.h>

typedef unsigned short u16;
typedef unsigned char u8;
typedef unsigned int u32;
typedef __bf16 bf16x8 __attribute__((ext_vector_type(8)));
typedef float f32x4 __attribute__((ext_vector_type(4)));

#define NL 41
#define HW 16384

// ws layout (bytes)
#define NHWC_OFF   0            // 8*16384*256 bf16 = 67,108,864
#define WA_OFF     67108864     // 576*64*8 bf16 = 589,824
#define LAB8_OFF   67698688     // 8*16384 u8 = 131,072
#define GHIST_OFF  67829760     // 8*41 int (pad 2048)
#define SUMS_OFF   67831808     // 2*8*41*128 f32 = 335,872
#define GATES_OFF  68167680     // 2*8*128 f32

__device__ __forceinline__ u16 f2bf(float f) {
    u32 u = __builtin_bit_cast(u32, f);
    u = (u + 0x7FFFu + ((u >> 16) & 1u)) >> 16;
    return (u16)u;
}

__device__ __forceinline__ void glds16(const void* g, void* l) {
    __builtin_amdgcn_global_load_lds(
        (const __attribute__((address_space(1))) void*)g,
        (__attribute__((address_space(3))) void*)l, 16, 0, 0);
}

// ---------------------------------------------------------------------------
// K0a: weight repack -> Wa[(chunk*9+tap)*8+ct][lane][8] bf16 (A-frag lane order)
// Block 0 zeroes ghist (this kernel runs BEFORE k_prep, which accumulates it).
// ---------------------------------------------------------------------------
__global__ __launch_bounds__(64)
void k_wpack(const float* __restrict__ w, u16* __restrict__ wa, int* __restrict__ ghist)
{
    const int bid = (int)blockIdx.x;        // kt*8 + ct, 576 blocks
    const int l = (int)threadIdx.x;
    if (bid == 0) {
        for (int i = l; i < 8 * NL; i += 64) ghist[i] = 0;
    }
    const int kt = bid >> 3, ct = bid & 7;
    const int chunk = kt / 9, tap = kt - chunk * 9;
    const int co = ct * 16 + (l & 15);
    const int cin0 = chunk * 32 + (l >> 4) * 8;
    u16 tmp[8];
#pragma unroll
    for (int j = 0; j < 8; ++j)
        tmp[j] = f2bf(w[((size_t)co * 256 + cin0 + j) * 9 + tap]);
    *(f32x4*)&wa[((size_t)bid * 64 + l) * 8] = *(f32x4*)tmp;
}

// ---------------------------------------------------------------------------
// K0b: fused add/mul -> bf16 NHWC [b][px][c'] (c'<128 = r+d, 128+c = r*sig(d)).
// Also: nearest-sample labels -> lab8[b][px] u8, per-block LDS hist -> ghist.
// 2048 blocks (8b x 256 chunks of 64 px), 256 thr.
// ---------------------------------------------------------------------------
__global__ __launch_bounds__(256, 4)
void k_prep(const float* __restrict__ r, const float* __restrict__ d,
            const int* __restrict__ label, u16* __restrict__ nhwc,
            u8* __restrict__ lab8, int* __restrict__ ghist)
{
    __shared__ u16 s[64 * 256];             // [px][c'] 32 KB
    __shared__ int hist[NL];
    const int bid = (int)blockIdx.x;
    const int b = bid >> 8;
    const int px0 = (bid & 255) * 64;
    const int tid = (int)threadIdx.x;
    const int c = tid & 127;
    const int half = tid >> 7;              // px half 0/1

    if (tid < NL) hist[tid] = 0;
    // wave 0: program order guarantees init (tid<41) before atomics (tid<64)
    if (tid < 64) {
        int px = px0 + tid;
        int yy = px >> 7, xx = px & 127;
        int lab = label[(size_t)b * 512 * 512 + (yy * 4) * 512 + xx * 4];
        lab8[b * HW + px] = (u8)lab;
        atomicAdd(&hist[lab], 1);
    }

    const float* rp = r + ((size_t)(b * 128 + c)) * HW + px0 + half * 32;
    const float* dp = d + ((size_t)(b * 128 + c)) * HW + px0 + half * 32;
#pragma unroll
    for (int j = 0; j < 8; ++j) {
        float4 rv = *(const float4*)(rp + j * 4);
        float4 dv = *(const float4*)(dp + j * 4);
        float ra[4] = {rv.x, rv.y, rv.z, rv.w};
        float da[4] = {dv.x, dv.y, dv.z, dv.w};
#pragma unroll
        for (int i = 0; i < 4; ++i) {
            int px = half * 32 + j * 4 + i;
            s[px * 256 + c] = f2bf(ra[i] + da[i]);
            s[px * 256 + 128 + c] = f2bf(ra[i] / (1.f + __expf(-da[i])));
        }
    }
    __syncthreads();
    const f32x4* sf = (const f32x4*)s;
    f32x4* dst = (f32x4*)nhwc + ((size_t)b * HW + px0) * 32;
#pragma unroll
    for (int k = 0; k < 8; ++k) {
        int fi = k * 256 + tid;
        dst[fi] = sf[fi];
    }
    if (tid < NL && hist[tid] > 0) atomicAdd(&ghist[b * NL + tid], hist[tid]);
}

// ---------------------------------------------------------------------------
// K1: conv3x3 implicit GEMM, bf16 MFMA 16x16x32, double-buffered LDS.
// Block: 2 rows x 128 px x 128 co; 4 waves (wr,wc), wave tile 64co x 128px.
// grid 512, bid = rowpair*8 + b (batch-per-XCD locality; FETCH ~80 MB).
// LDS granule (row 0..3, xslot 0..129, ci8 0..3) = 2080 x 16 B per buffer.
// Pipeline: stage(k+1) issued right after the barrier that published stage(k);
// A-frags 2-deep prefetched BEFORE staging so early taps don't FIFO-wait on it.
// ---------------------------------------------------------------------------
__global__ __launch_bounds__(256, 2)
void k_conv(const u16* __restrict__ nhwc, const u16* __restrict__ wa,
            float* __restrict__ out)
{
    __shared__ u16 s_in[2 * 2080 * 8];      // 2 x 33280 B
    const int tid = (int)threadIdx.x;
    const int bid = (int)blockIdx.x;
    const int b = bid & 7;
    const int y0 = (bid >> 3) * 2;
    const int l = tid & 63;
    const int wv = tid >> 6;
    const int wr = wv & 1;                  // image row within pair
    const int wc = wv >> 1;                 // co half
    const int l15 = l & 15;
    const int l16 = l >> 4;

    {   // zero BOTH buffers once; halo granules stay zero forever
        f32x4 zz = {0.f, 0.f, 0.f, 0.f};
        for (int i = tid; i < 4160; i += 256) ((f32x4*)s_in)[i] = zz;
    }

    // per-lane global byte offsets for 9 staging rounds (-1 = halo/masked)
    int goff[9];
#pragma unroll
    for (int it = 0; it < 9; ++it) {
        int s = it * 256 + tid;
        int row = s / 520;                  // 130 xslots * 4 ci8
        int rem = s - row * 520;
        int xslot = rem >> 2;
        int ci8 = rem & 3;
        int gy = y0 - 1 + row;
        int gx = xslot - 1;
        bool valid = (s < 2080) && ((unsigned)gy < 128u) && ((unsigned)gx < 128u);
        goff[it] = valid ? (((gy << 7) | gx) * 256 + ci8 * 8) * 2 : -1;
    }

    f32x4 acc[4][8];
#pragma unroll
    for (int i = 0; i < 4; ++i)
#pragma unroll
        for (int j = 0; j < 8; ++j) {
            f32x4 zz = {0.f, 0.f, 0.f, 0.f};
            acc[i][j] = zz;
        }

    const char* src_b = (const char*)(nhwc + (size_t)b * HW * 256);
    const int lane_base = (tid & 192) * 16;     // wave-uniform LDS base
    const f32x4* wa4 = (const f32x4*)wa;

    __syncthreads();                         // order zero ds_writes before glds
#pragma unroll
    for (int it = 0; it < 9; ++it)           // stage chunk 0 -> buf 0
        if (goff[it] >= 0)
            glds16(src_b + goff[it], (char*)s_in + it * 4096 + lane_base);

#pragma unroll 1
    for (int chunk = 0; chunk < 8; ++chunk) {
        __syncthreads();                     // publishes stage(chunk), frees other buf

        // A prefetch (taps 0,1) BEFORE next staging -> older in vmcnt FIFO
        f32x4 a0[4], a1[4];
        {
            int kt8 = chunk * 72;
#pragma unroll
            for (int i = 0; i < 4; ++i) a0[i] = wa4[(kt8 + wc * 4 + i) * 64 + l];
#pragma unroll
            for (int i = 0; i < 4; ++i) a1[i] = wa4[(kt8 + 8 + wc * 4 + i) * 64 + l];
        }
        if (chunk < 7) {                     // stage chunk+1 into other buffer
            char* dstb = (char*)s_in + ((chunk + 1) & 1) * 33280 + lane_base;
#pragma unroll
            for (int it = 0; it < 9; ++it)
                if (goff[it] >= 0)
                    glds16(src_b + goff[it] + (chunk + 1) * 64, dstb + it * 4096);
        }

        const char* bufp = (const char*)s_in + (chunk & 1) * 33280;
#pragma unroll
        for (int tap = 0; tap < 9; ++tap) {
            f32x4 aC[4];
#pragma unroll
            for (int i = 0; i < 4; ++i) aC[i] = a0[i];
#pragma unroll
            for (int i = 0; i < 4; ++i) a0[i] = a1[i];
            if (tap + 2 < 9) {
                int kt8 = chunk * 72 + (tap + 2) * 8;
#pragma unroll
                for (int i = 0; i < 4; ++i)
                    a1[i] = wa4[(kt8 + wc * 4 + i) * 64 + l];
            }
            const int rowi = wr + tap / 3;
            const int dxo = tap % 3;
            f32x4 bf[8];
#pragma unroll
            for (int p = 0; p < 8; ++p) {
                int e = (rowi * 130 + p * 16 + l15 + dxo) * 64 + l16 * 16;
                bf[p] = *(const f32x4*)(bufp + e);
            }
#pragma unroll
            for (int ct = 0; ct < 4; ++ct) {
                bf16x8 av = __builtin_bit_cast(bf16x8, aC[ct]);
#pragma unroll
                for (int p = 0; p < 8; ++p)
                    acc[ct][p] = __builtin_amdgcn_mfma_f32_16x16x32_bf16(
                        av, __builtin_bit_cast(bf16x8, bf[p]), acc[ct][p], 0, 0, 0);
            }
        }
    }

    // D: col = px = l&15, row = co = (l>>4)*4 + reg
    const int y = y0 + wr;
    float* outb = out + (size_t)b * 128 * HW + (size_t)y * 128;
#pragma unroll
    for (int ct = 0; ct < 4; ++ct)
#pragma unroll
        for (int p = 0; p < 8; ++p) {
            int x = p * 16 + l15;
#pragma unroll
            for (int rr = 0; rr < 4; ++rr) {
                int co = wc * 64 + ct * 16 + l16 * 4 + rr;
                outb[(size_t)co * HW + x] = acc[ct][p][rr];
            }
        }
}

// ---------------------------------------------------------------------------
// K2: segment sums, one block per (b, c, feat) channel plane -> fully
// coalesced 64 KB reads; per-wave LDS f32-atomic bins; writes sums directly.
// grid 2048 = b*256 + c*2 + feat.
// ---------------------------------------------------------------------------
__global__ __launch_bounds__(256)
void k_seg(const float* __restrict__ fuse, const float* __restrict__ d,
           const u8* __restrict__ lab8, float* __restrict__ sums)
{
    __shared__ float bins[4][NL];
    const int bid = (int)blockIdx.x;
    const int feat = bid & 1;
    const int c = (bid >> 1) & 127;
    const int b = bid >> 8;
    const int tid = (int)threadIdx.x;
    const int w = tid >> 6;

    for (int i = tid; i < 4 * NL; i += 256) ((float*)bins)[i] = 0.f;
    __syncthreads();

    const float* src = (feat ? d : fuse) + ((size_t)(b * 128 + c)) * HW;
    const u8* lp = lab8 + b * HW;

#pragma unroll 4
    for (int k = 0; k < 16; ++k) {
        int i = k * 256 + tid;              // float4 index
        float4 v = ((const float4*)src)[i];
        uchar4 lv = ((const uchar4*)lp)[i];
        atomicAdd(&bins[w][lv.x], v.x);
        atomicAdd(&bins[w][lv.y], v.y);
        atomicAdd(&bins[w][lv.z], v.z);
        atomicAdd(&bins[w][lv.w], v.w);
    }
    __syncthreads();
    if (tid < NL) {
        float s = bins[0][tid] + bins[1][tid] + bins[2][tid] + bins[3][tid];
        sums[(size_t)((b * 2 + feat) * NL + tid) * 128 + c] = s;
    }
}

// ---------------------------------------------------------------------------
// K3: mean/base select + L2-normalize over classes + SE MLP -> gates.
// ---------------------------------------------------------------------------
__global__ __launch_bounds__(128)
void k_gates(const float* __restrict__ sums, const int* __restrict__ ghist,
             const float* __restrict__ base_f, const float* __restrict__ base_d,
             const float* __restrict__ f_w1, const float* __restrict__ f_w2,
             const float* __restrict__ d_w1, const float* __restrict__ d_w2,
             float* __restrict__ gates)
{
    __shared__ float sv[128];
    __shared__ float h1[8];
    const int b = (int)blockIdx.x >> 1;
    const int feat = (int)blockIdx.x & 1;
    const int c = (int)threadIdx.x;

    const float* base = feat ? base_d : base_f;
    float suma = 0.f, sumsq = 0.f;
    for (int lc = 0; lc < NL; ++lc) {
        float s = sums[(size_t)((b * 2 + feat) * NL + lc) * 128 + c];
        int cnt = ghist[b * NL + lc];
        float att = (cnt > 0) ? (s / (float)cnt) : base[(b * NL + lc) * 128 + c];
        suma += att;
        sumsq += att * att;
    }
    sv[c] = suma / fmaxf(sqrtf(sumsq), 1e-12f);
    __syncthreads();

    const float* w1 = feat ? d_w1 : f_w1;
    const float* w2 = feat ? d_w2 : f_w2;
    if (c < 8) {
        float h = 0.f;
        for (int k = 0; k < 128; ++k) h += w1[c * 128 + k] * sv[k];
        h1[c] = fmaxf(h, 0.f);
    }
    __syncthreads();

    float gv = 0.f;
#pragma unroll
    for (int o = 0; o < 8; ++o) gv += w2[c * 8 + o] * h1[o];
    gates[feat * 1024 + b * 128 + c] = 1.f / (1.f + expf(-gv));
}

// ---------------------------------------------------------------------------
// K4: out = fuse * g_f + d * g_d (fuse in-place in d_out).
// ---------------------------------------------------------------------------
__global__ __launch_bounds__(256)
void k_final(const float* __restrict__ d, const float* __restrict__ gates,
             float* out)
{
    size_t t4 = (size_t)blockIdx.x * 256 + threadIdx.x;
    size_t basei = t4 * 4;
    int bc = (int)(basei >> 14);
    float gf = gates[bc];
    float gd = gates[1024 + bc];
    float4 f = *(const float4*)(out + basei);
    float4 dv = *(const float4*)(d + basei);
    float4 o;
    o.x = f.x * gf + dv.x * gd;
    o.y = f.y * gf + dv.y * gd;
    o.z = f.z * gf + dv.z * gd;
    o.w = f.w * gf + dv.w * gd;
    *(float4*)(out + basei) = o;
}

extern "C" void kernel_launch(void* const* d_in, const int* in_sizes, int n_in,
                              void* d_out, int out_size, void* d_ws, size_t ws_size,
                              hipStream_t stream)
{
    (void)in_sizes; (void)n_in; (void)out_size; (void)ws_size;
    const float* r      = (const float*)d_in[0];
    const float* d      = (const float*)d_in[1];
    const int*   label  = (const int*)d_in[2];
    const float* conv_w = (const float*)d_in[3];
    const float* f_w1   = (const float*)d_in[4];
    const float* f_w2   = (const float*)d_in[5];
    const float* d_w1   = (const float*)d_in[6];
    const float* d_w2   = (const float*)d_in[7];
    const float* base_f = (const float*)d_in[8];
    const float* base_d = (const float*)d_in[9];
    float* out = (float*)d_out;

    char* ws = (char*)d_ws;
    u16* nhwc    = (u16*)(ws + NHWC_OFF);
    u16* wa      = (u16*)(ws + WA_OFF);
    u8*  lab8    = (u8*)(ws + LAB8_OFF);
    int* ghist   = (int*)(ws + GHIST_OFF);
    float* sums  = (float*)(ws + SUMS_OFF);
    float* gates = (float*)(ws + GATES_OFF);

    hipLaunchKernelGGL(k_wpack, dim3(576), dim3(64), 0, stream, conv_w, wa, ghist);
    hipLaunchKernelGGL(k_prep, dim3(2048), dim3(256), 0, stream, r, d, label,
                       nhwc, lab8, ghist);
    hipLaunchKernelGGL(k_conv, dim3(512), dim3(256), 0, stream, nhwc, wa, out);
    hipLaunchKernelGGL(k_seg, dim3(2048), dim3(256), 0, stream, out, d, lab8, sums);
    hipLaunchKernelGGL(k_gates, dim3(16), dim3(128), 0, stream, sums, ghist,
                       base_f, base_d, f_w1, f_w2, d_w1, d_w2, gates);
    hipLaunchKernelGGL(k_final, dim3(16384), dim3(256), 0, stream, d, gates, out);
}

// Round 5
// 363.499 us; speedup vs baseline: 1.3631x; 1.3631x over previous
//
#include <hip/hip_runtime.h>
#include <math.h>

typedef unsigned short u16;
typedef unsigned char u8;
typedef unsigned int u32;
typedef __bf16 bf16x8 __attribute__((ext_vector_type(8)));
typedef float f32x4 __attribute__((ext_vector_type(4)));

#define NL 41
#define HW 16384

// ws layout (bytes)
#define NHWC_OFF   0            // 8*16384*256 bf16 = 67,108,864
#define WA_OFF     67108864     // 576*64*8 bf16 = 589,824
#define LAB8_OFF   67698688     // 8*16384 u8 = 131,072
#define GHIST_OFF  67829760     // 8*41 int (pad 2048)
#define SUMS_OFF   67831808     // 2*8*41*128 f32 = 335,872
#define GATES_OFF  68167680     // 2*8*128 f32

__device__ __forceinline__ u16 f2bf(float f) {
    u32 u = __builtin_bit_cast(u32, f);
    u = (u + 0x7FFFu + ((u >> 16) & 1u)) >> 16;
    return (u16)u;
}

__device__ __forceinline__ void glds16(const void* g, void* l) {
    __builtin_amdgcn_global_load_lds(
        (const __attribute__((address_space(1))) void*)g,
        (__attribute__((address_space(3))) void*)l, 16, 0, 0);
}

// ---------------------------------------------------------------------------
// K0a: weight repack -> Wa[(chunk*9+tap)*8+ct][lane][8] bf16 (A-frag lane order)
// Block 0 zeroes ghist (this kernel runs BEFORE k_prep, which accumulates it).
// ---------------------------------------------------------------------------
__global__ __launch_bounds__(64)
void k_wpack(const float* __restrict__ w, u16* __restrict__ wa, int* __restrict__ ghist)
{
    const int bid = (int)blockIdx.x;        // kt*8 + ct, 576 blocks
    const int l = (int)threadIdx.x;
    if (bid == 0) {
        for (int i = l; i < 8 * NL; i += 64) ghist[i] = 0;
    }
    const int kt = bid >> 3, ct = bid & 7;
    const int chunk = kt / 9, tap = kt - chunk * 9;
    const int co = ct * 16 + (l & 15);
    const int cin0 = chunk * 32 + (l >> 4) * 8;
    u16 tmp[8];
#pragma unroll
    for (int j = 0; j < 8; ++j)
        tmp[j] = f2bf(w[((size_t)co * 256 + cin0 + j) * 9 + tap]);
    *(f32x4*)&wa[((size_t)bid * 64 + l) * 8] = *(f32x4*)tmp;
}

// ---------------------------------------------------------------------------
// K0b: fused add/mul -> bf16 NHWC [b][px][c'] (c'<128 = r+d, 128+c = r*sig(d)).
// Also: nearest-sample labels -> lab8[b][px] u8, per-block LDS hist -> ghist.
// 2048 blocks (8b x 256 chunks of 64 px), 256 thr.
// ---------------------------------------------------------------------------
__global__ __launch_bounds__(256, 4)
void k_prep(const float* __restrict__ r, const float* __restrict__ d,
            const int* __restrict__ label, u16* __restrict__ nhwc,
            u8* __restrict__ lab8, int* __restrict__ ghist)
{
    __shared__ u16 s[64 * 256];             // [px][c'] 32 KB
    __shared__ int hist[NL];
    const int bid = (int)blockIdx.x;
    const int b = bid >> 8;
    const int px0 = (bid & 255) * 64;
    const int tid = (int)threadIdx.x;
    const int c = tid & 127;
    const int half = tid >> 7;              // px half 0/1

    if (tid < NL) hist[tid] = 0;
    // wave 0: program order guarantees init (tid<41) before atomics (tid<64)
    if (tid < 64) {
        int px = px0 + tid;
        int yy = px >> 7, xx = px & 127;
        int lab = label[(size_t)b * 512 * 512 + (yy * 4) * 512 + xx * 4];
        lab8[b * HW + px] = (u8)lab;
        atomicAdd(&hist[lab], 1);
    }

    const float* rp = r + ((size_t)(b * 128 + c)) * HW + px0 + half * 32;
    const float* dp = d + ((size_t)(b * 128 + c)) * HW + px0 + half * 32;
#pragma unroll
    for (int j = 0; j < 8; ++j) {
        float4 rv = *(const float4*)(rp + j * 4);
        float4 dv = *(const float4*)(dp + j * 4);
        float ra[4] = {rv.x, rv.y, rv.z, rv.w};
        float da[4] = {dv.x, dv.y, dv.z, dv.w};
#pragma unroll
        for (int i = 0; i < 4; ++i) {
            int px = half * 32 + j * 4 + i;
            s[px * 256 + c] = f2bf(ra[i] + da[i]);
            s[px * 256 + 128 + c] = f2bf(ra[i] / (1.f + __expf(-da[i])));
        }
    }
    __syncthreads();
    const f32x4* sf = (const f32x4*)s;
    f32x4* dst = (f32x4*)nhwc + ((size_t)b * HW + px0) * 32;
#pragma unroll
    for (int k = 0; k < 8; ++k) {
        int fi = k * 256 + tid;
        dst[fi] = sf[fi];
    }
    if (tid < NL && hist[tid] > 0) atomicAdd(&ghist[b * NL + tid], hist[tid]);
}

// ---------------------------------------------------------------------------
// K1: conv3x3 implicit GEMM, bf16 MFMA 16x16x32, double-buffered LDS.
// Block: 2 rows x 128 px x 128 co; 4 waves (wr,wc), wave tile 64co x 128px.
// grid 512, bid = rowpair*8 + b. (unchanged from round 4)
// ---------------------------------------------------------------------------
__global__ __launch_bounds__(256, 2)
void k_conv(const u16* __restrict__ nhwc, const u16* __restrict__ wa,
            float* __restrict__ out)
{
    __shared__ u16 s_in[2 * 2080 * 8];      // 2 x 33280 B
    const int tid = (int)threadIdx.x;
    const int bid = (int)blockIdx.x;
    const int b = bid & 7;
    const int y0 = (bid >> 3) * 2;
    const int l = tid & 63;
    const int wv = tid >> 6;
    const int wr = wv & 1;                  // image row within pair
    const int wc = wv >> 1;                 // co half
    const int l15 = l & 15;
    const int l16 = l >> 4;

    {   // zero BOTH buffers once; halo granules stay zero forever
        f32x4 zz = {0.f, 0.f, 0.f, 0.f};
        for (int i = tid; i < 4160; i += 256) ((f32x4*)s_in)[i] = zz;
    }

    // per-lane global byte offsets for 9 staging rounds (-1 = halo/masked)
    int goff[9];
#pragma unroll
    for (int it = 0; it < 9; ++it) {
        int s = it * 256 + tid;
        int row = s / 520;                  // 130 xslots * 4 ci8
        int rem = s - row * 520;
        int xslot = rem >> 2;
        int ci8 = rem & 3;
        int gy = y0 - 1 + row;
        int gx = xslot - 1;
        bool valid = (s < 2080) && ((unsigned)gy < 128u) && ((unsigned)gx < 128u);
        goff[it] = valid ? (((gy << 7) | gx) * 256 + ci8 * 8) * 2 : -1;
    }

    f32x4 acc[4][8];
#pragma unroll
    for (int i = 0; i < 4; ++i)
#pragma unroll
        for (int j = 0; j < 8; ++j) {
            f32x4 zz = {0.f, 0.f, 0.f, 0.f};
            acc[i][j] = zz;
        }

    const char* src_b = (const char*)(nhwc + (size_t)b * HW * 256);
    const int lane_base = (tid & 192) * 16;     // wave-uniform LDS base
    const f32x4* wa4 = (const f32x4*)wa;

    __syncthreads();                         // order zero ds_writes before glds
#pragma unroll
    for (int it = 0; it < 9; ++it)           // stage chunk 0 -> buf 0
        if (goff[it] >= 0)
            glds16(src_b + goff[it], (char*)s_in + it * 4096 + lane_base);

#pragma unroll 1
    for (int chunk = 0; chunk < 8; ++chunk) {
        __syncthreads();                     // publishes stage(chunk), frees other buf

        // A prefetch (taps 0,1) BEFORE next staging -> older in vmcnt FIFO
        f32x4 a0[4], a1[4];
        {
            int kt8 = chunk * 72;
#pragma unroll
            for (int i = 0; i < 4; ++i) a0[i] = wa4[(kt8 + wc * 4 + i) * 64 + l];
#pragma unroll
            for (int i = 0; i < 4; ++i) a1[i] = wa4[(kt8 + 8 + wc * 4 + i) * 64 + l];
        }
        if (chunk < 7) {                     // stage chunk+1 into other buffer
            char* dstb = (char*)s_in + ((chunk + 1) & 1) * 33280 + lane_base;
#pragma unroll
            for (int it = 0; it < 9; ++it)
                if (goff[it] >= 0)
                    glds16(src_b + goff[it] + (chunk + 1) * 64, dstb + it * 4096);
        }

        const char* bufp = (const char*)s_in + (chunk & 1) * 33280;
#pragma unroll
        for (int tap = 0; tap < 9; ++tap) {
            f32x4 aC[4];
#pragma unroll
            for (int i = 0; i < 4; ++i) aC[i] = a0[i];
#pragma unroll
            for (int i = 0; i < 4; ++i) a0[i] = a1[i];
            if (tap + 2 < 9) {
                int kt8 = chunk * 72 + (tap + 2) * 8;
#pragma unroll
                for (int i = 0; i < 4; ++i)
                    a1[i] = wa4[(kt8 + wc * 4 + i) * 64 + l];
            }
            const int rowi = wr + tap / 3;
            const int dxo = tap % 3;
            f32x4 bf[8];
#pragma unroll
            for (int p = 0; p < 8; ++p) {
                int e = (rowi * 130 + p * 16 + l15 + dxo) * 64 + l16 * 16;
                bf[p] = *(const f32x4*)(bufp + e);
            }
#pragma unroll
            for (int ct = 0; ct < 4; ++ct) {
                bf16x8 av = __builtin_bit_cast(bf16x8, aC[ct]);
#pragma unroll
                for (int p = 0; p < 8; ++p)
                    acc[ct][p] = __builtin_amdgcn_mfma_f32_16x16x32_bf16(
                        av, __builtin_bit_cast(bf16x8, bf[p]), acc[ct][p], 0, 0, 0);
            }
        }
    }

    // D: col = px = l&15, row = co = (l>>4)*4 + reg
    const int y = y0 + wr;
    float* outb = out + (size_t)b * 128 * HW + (size_t)y * 128;
#pragma unroll
    for (int ct = 0; ct < 4; ++ct)
#pragma unroll
        for (int p = 0; p < 8; ++p) {
            int x = p * 16 + l15;
#pragma unroll
            for (int rr = 0; rr < 4; ++rr) {
                int co = wc * 64 + ct * 16 + l16 * 4 + rr;
                outb[(size_t)co * HW + x] = acc[ct][p][rr];
            }
        }
}

// ---------------------------------------------------------------------------
// K2: segment sums, one block per (b, c, feat) channel plane -> fully
// coalesced 64 KB reads. LDS bins[41][256], thread owns column tid:
// read-modify-write, bank = tid%32 -> 2-way aliasing (free), NO atomics,
// no data-dependent conflicts. Tree-reduce columns, write sums.
// grid 2048 = b*256 + c*2 + feat.
// ---------------------------------------------------------------------------
__global__ __launch_bounds__(256, 3)
void k_seg(const float* __restrict__ fuse, const float* __restrict__ d,
           const u8* __restrict__ lab8, float* __restrict__ sums)
{
    __shared__ float bins[NL][256];         // 41984 B
    const int bid = (int)blockIdx.x;
    const int feat = bid & 1;
    const int c = (bid >> 1) & 127;
    const int b = bid >> 8;
    const int tid = (int)threadIdx.x;

    for (int i = tid; i < NL * 256; i += 256) ((float*)bins)[i] = 0.f;
    __syncthreads();

    const float* src = (feat ? d : fuse) + ((size_t)(b * 128 + c)) * HW;
    const u8* lp = lab8 + b * HW;

#pragma unroll 4
    for (int k = 0; k < 16; ++k) {
        int i = k * 256 + tid;              // float4 index
        float4 v = ((const float4*)src)[i];
        uchar4 lv = ((const uchar4*)lp)[i];
        bins[lv.x][tid] += v.x;
        bins[lv.y][tid] += v.y;
        bins[lv.z][tid] += v.z;
        bins[lv.w][tid] += v.w;
    }
    __syncthreads();

    // tree-reduce 256 columns -> column 0 (per class row)
    for (int stride = 128; stride >= 1; stride >>= 1) {
        for (int idx = tid; idx < NL * stride; idx += 256) {
            int l = idx / stride;
            int cc = idx - l * stride;
            bins[l][cc] += bins[l][cc + stride];
        }
        __syncthreads();
    }
    if (tid < NL)
        sums[(size_t)((b * 2 + feat) * NL + tid) * 128 + c] = bins[tid][0];
}

// ---------------------------------------------------------------------------
// K3: mean/base select + L2-normalize over classes + SE MLP -> gates.
// ---------------------------------------------------------------------------
__global__ __launch_bounds__(128)
void k_gates(const float* __restrict__ sums, const int* __restrict__ ghist,
             const float* __restrict__ base_f, const float* __restrict__ base_d,
             const float* __restrict__ f_w1, const float* __restrict__ f_w2,
             const float* __restrict__ d_w1, const float* __restrict__ d_w2,
             float* __restrict__ gates)
{
    __shared__ float sv[128];
    __shared__ float h1[8];
    const int b = (int)blockIdx.x >> 1;
    const int feat = (int)blockIdx.x & 1;
    const int c = (int)threadIdx.x;

    const float* base = feat ? base_d : base_f;
    float suma = 0.f, sumsq = 0.f;
    for (int lc = 0; lc < NL; ++lc) {
        float s = sums[(size_t)((b * 2 + feat) * NL + lc) * 128 + c];
        int cnt = ghist[b * NL + lc];
        float att = (cnt > 0) ? (s / (float)cnt) : base[(b * NL + lc) * 128 + c];
        suma += att;
        sumsq += att * att;
    }
    sv[c] = suma / fmaxf(sqrtf(sumsq), 1e-12f);
    __syncthreads();

    const float* w1 = feat ? d_w1 : f_w1;
    const float* w2 = feat ? d_w2 : f_w2;
    if (c < 8) {
        float h = 0.f;
        for (int k = 0; k < 128; ++k) h += w1[c * 128 + k] * sv[k];
        h1[c] = fmaxf(h, 0.f);
    }
    __syncthreads();

    float gv = 0.f;
#pragma unroll
    for (int o = 0; o < 8; ++o) gv += w2[c * 8 + o] * h1[o];
    gates[feat * 1024 + b * 128 + c] = 1.f / (1.f + expf(-gv));
}

// ---------------------------------------------------------------------------
// K4: out = fuse * g_f + d * g_d (fuse in-place in d_out).
// ---------------------------------------------------------------------------
__global__ __launch_bounds__(256)
void k_final(const float* __restrict__ d, const float* __restrict__ gates,
             float* out)
{
    size_t t4 = (size_t)blockIdx.x * 256 + threadIdx.x;
    size_t basei = t4 * 4;
    int bc = (int)(basei >> 14);
    float gf = gates[bc];
    float gd = gates[1024 + bc];
    float4 f = *(const float4*)(out + basei);
    float4 dv = *(const float4*)(d + basei);
    float4 o;
    o.x = f.x * gf + dv.x * gd;
    o.y = f.y * gf + dv.y * gd;
    o.z = f.z * gf + dv.z * gd;
    o.w = f.w * gf + dv.w * gd;
    *(float4*)(out + basei) = o;
}

extern "C" void kernel_launch(void* const* d_in, const int* in_sizes, int n_in,
                              void* d_out, int out_size, void* d_ws, size_t ws_size,
                              hipStream_t stream)
{
    (void)in_sizes; (void)n_in; (void)out_size; (void)ws_size;
    const float* r      = (const float*)d_in[0];
    const float* d      = (const float*)d_in[1];
    const int*   label  = (const int*)d_in[2];
    const float* conv_w = (const float*)d_in[3];
    const float* f_w1   = (const float*)d_in[4];
    const float* f_w2   = (const float*)d_in[5];
    const float* d_w1   = (const float*)d_in[6];
    const float* d_w2   = (const float*)d_in[7];
    const float* base_f = (const float*)d_in[8];
    const float* base_d = (const float*)d_in[9];
    float* out = (float*)d_out;

    char* ws = (char*)d_ws;
    u16* nhwc    = (u16*)(ws + NHWC_OFF);
    u16* wa      = (u16*)(ws + WA_OFF);
    u8*  lab8    = (u8*)(ws + LAB8_OFF);
    int* ghist   = (int*)(ws + GHIST_OFF);
    float* sums  = (float*)(ws + SUMS_OFF);
    float* gates = (float*)(ws + GATES_OFF);

    hipLaunchKernelGGL(k_wpack, dim3(576), dim3(64), 0, stream, conv_w, wa, ghist);
    hipLaunchKernelGGL(k_prep, dim3(2048), dim3(256), 0, stream, r, d, label,
                       nhwc, lab8, ghist);
    hipLaunchKernelGGL(k_conv, dim3(512), dim3(256), 0, stream, nhwc, wa, out);
    hipLaunchKernelGGL(k_seg, dim3(2048), dim3(256), 0, stream, out, d, lab8, sums);
    hipLaunchKernelGGL(k_gates, dim3(16), dim3(128), 0, stream, sums, ghist,
                       base_f, base_d, f_w1, f_w2, d_w1, d_w2, gates);
    hipLaunchKernelGGL(k_final, dim3(16384), dim3(256), 0, stream, d, gates, out);
}